// Round 6
// baseline (683.499 us; speedup 1.0000x reference)
//
#include <hip/hip_runtime.h>
#include <math.h>

// Problem constants (from reference)
#define BG    100        // graphs
#define NPG   500        // nodes per graph (layer 1)
#define FD    128        // feature dim (F_IN == H == 128)
#define EE    600000     // edges
#define NN    50000      // total nodes layer 1
#define K1    250
#define K2    125
#define K3    63
#define CAP   64         // max in-degree capacity (in-deg ~ Poisson(12); P(>64) ~ 1e-30)

// ---------------- slot-CSR build: one edge pass, no scan ----------------
__global__ void fill_first_kernel(const int* __restrict__ ei, int* __restrict__ deg,
                                  int* __restrict__ col, int E) {
    int e = blockIdx.x * blockDim.x + threadIdx.x;
    if (e >= E) return;
    int d = ei[E + e];
    int pos = atomicAdd(&deg[d], 1);
    if (pos < CAP) col[d * CAP + pos] = ei[e];
}

// remap original edges through layer-1 pooling, store remapped edges for layer 3,
// and fill layer-2 neighbor slots — all in one pass
__global__ void remap_fill_first_kernel(const int* __restrict__ ei, const int* __restrict__ mapping,
                                        int* __restrict__ src, int* __restrict__ dst,
                                        float* __restrict__ em, int* __restrict__ deg,
                                        int* __restrict__ col, int E) {
    int e = blockIdx.x * blockDim.x + threadIdx.x;
    if (e >= E) return;
    int ns = mapping[ei[e]], nd = mapping[ei[E + e]];
    bool keep = (ns >= 0) && (nd >= 0);
    em[e]  = keep ? 1.0f : 0.0f;
    src[e] = keep ? ns : 0;
    dst[e] = keep ? nd : 0;
    if (keep) {
        int pos = atomicAdd(&deg[nd], 1);
        if (pos < CAP) col[nd * CAP + pos] = ns;
    }
}

// remap layer-2 edges through layer-2 pooling and fill layer-3 slots
__global__ void remap_fill_kernel(const int* __restrict__ src, const int* __restrict__ dst,
                                  const float* __restrict__ em, const int* __restrict__ mapping,
                                  int* __restrict__ deg, int* __restrict__ col, int E) {
    int e = blockIdx.x * blockDim.x + threadIdx.x;
    if (e >= E) return;
    if (em[e] == 0.0f) return;
    int ns = mapping[src[e]], nd = mapping[dst[e]];
    if (ns >= 0 && nd >= 0) {
        int pos = atomicAdd(&deg[nd], 1);
        if (pos < CAP) col[nd * CAP + pos] = ns;
    }
}

// ---------------- fused gather-mean + SAGE GEMM + score epilogue ----------------
// h = relu(mean@Wl + x@Wr + bl); score = tanh(h.pw / ||pw||)
// Tile 64 rows x 128 cols, 128 threads, 8x8 micro-tile.
// Phase 0 gathers per-node neighbor means transposed into meanT[k][row] (stride 68),
// which serves directly as the A-fragment source for the mean half of K.
__global__ __launch_bounds__(128) void sage_gemm_fused_kernel(
        const int* __restrict__ deg, const int* __restrict__ col,
        const float* __restrict__ x,
        const float* __restrict__ Wl, const float* __restrict__ Wr,
        const float* __restrict__ bl, const float* __restrict__ pw,
        float* __restrict__ hout, float* __restrict__ score, int M) {
    __shared__ __align__(16) float meanT[128 * 68];  // [k][row]
    __shared__ __align__(16) float Asx[32 * 68];     // x-half staging [kk][row]
    __shared__ __align__(16) float Ws[32 * 128];     // [kk][col]
    __shared__ float spart[64 * 16];
    __shared__ float snrmp[16];
    int tid  = threadIdx.x;
    int row0 = blockIdx.x * 64;

    // ---- phase 0: gather means (same neighbor order as slot list -> bitwise stable) ----
    {
        int grp = tid >> 5, sub = tid & 31;
        for (int nb = 0; nb < 16; ++nb) {
            int row  = (nb << 2) + grp;
            int node = row0 + row;
            if (node < M) {
                int d = deg[node]; if (d > CAP) d = CAP;
                const int* cp = col + node * CAP;
                float ax = 0.f, ay = 0.f, az = 0.f, aw = 0.f;
                for (int j = 0; j < d; ++j) {
                    float4 v = ((const float4*)(x + (long long)cp[j] * FD))[sub];
                    ax += v.x; ay += v.y; az += v.z; aw += v.w;
                }
                float inv = 1.0f / fmaxf((float)d, 1.0f);
                int k0 = sub << 2;
                meanT[(k0 + 0) * 68 + row] = ax * inv;
                meanT[(k0 + 1) * 68 + row] = ay * inv;
                meanT[(k0 + 2) * 68 + row] = az * inv;
                meanT[(k0 + 3) * 68 + row] = aw * inv;
            }
        }
    }
    // (covered by the barrier after kt=0 staging below)

    int tr = tid >> 4;               // 0..7  -> rows 8*tr..8*tr+7
    int tc = tid & 15;               // 0..15 -> cols {4tc..4tc+3, 64+4tc..64+4tc+3}
    float acc[8][8];
#pragma unroll
    for (int r = 0; r < 8; r++)
#pragma unroll
        for (int c = 0; c < 8; c++) acc[r][c] = 0.0f;

    int lrow = tid >> 1;             // 0..63
    int lk16 = (tid & 1) << 4;       // 0 or 16
    int wc   = (tid & 31) << 2;      // 0..124
    int wk0  = tid >> 5;             // 0..3

    for (int kt = 0; kt < 8; ++kt) {
        bool isMean = kt < 4;
        if (!isMean) {
            int grow = row0 + lrow; if (grow > M - 1) grow = M - 1;
            const float* xr = x + (long long)grow * FD + (kt - 4) * 32 + lk16;
#pragma unroll
            for (int q = 0; q < 4; ++q) {
                float4 v = *(const float4*)(xr + (q << 2));
                int kb = lk16 + (q << 2);
                Asx[(kb + 0) * 68 + lrow] = v.x;
                Asx[(kb + 1) * 68 + lrow] = v.y;
                Asx[(kb + 2) * 68 + lrow] = v.z;
                Asx[(kb + 3) * 68 + lrow] = v.w;
            }
        }
        {
            const float* WB = isMean ? Wl : Wr;
            int krow0 = (isMean ? kt : kt - 4) * 32;
#pragma unroll
            for (int q = 0; q < 8; ++q) {
                int kk = wk0 + (q << 2);
                *(float4*)&Ws[kk * 128 + wc] = *(const float4*)(WB + (long long)(krow0 + kk) * FD + wc);
            }
        }
        __syncthreads();
        const float* Ab = isMean ? (meanT + kt * 32 * 68) : Asx;
#pragma unroll
        for (int kk = 0; kk < 32; ++kk) {
            float4 a0 = *(const float4*)&Ab[kk * 68 + tr * 8];
            float4 a1 = *(const float4*)&Ab[kk * 68 + tr * 8 + 4];
            float4 b0 = *(const float4*)&Ws[kk * 128 + tc * 4];
            float4 b1 = *(const float4*)&Ws[kk * 128 + 64 + tc * 4];
            float av[8] = {a0.x, a0.y, a0.z, a0.w, a1.x, a1.y, a1.z, a1.w};
            float bv[8] = {b0.x, b0.y, b0.z, b0.w, b1.x, b1.y, b1.z, b1.w};
#pragma unroll
            for (int r = 0; r < 8; r++)
#pragma unroll
                for (int c = 0; c < 8; c++) acc[r][c] += av[r] * bv[c];
        }
        __syncthreads();
    }

    // epilogue: bias + relu + store h, score partials
    float4 bb0 = *(const float4*)(bl + tc * 4);
    float4 bb1 = *(const float4*)(bl + 64 + tc * 4);
    float4 w0  = *(const float4*)(pw + tc * 4);
    float4 w1  = *(const float4*)(pw + 64 + tc * 4);
    float bvec[8] = {bb0.x, bb0.y, bb0.z, bb0.w, bb1.x, bb1.y, bb1.z, bb1.w};
    float wvec[8] = {w0.x, w0.y, w0.z, w0.w, w1.x, w1.y, w1.z, w1.w};
    if (tr == 0) snrmp[tc] = w0.x*w0.x + w0.y*w0.y + w0.z*w0.z + w0.w*w0.w +
                             w1.x*w1.x + w1.y*w1.y + w1.z*w1.z + w1.w*w1.w;
#pragma unroll
    for (int r = 0; r < 8; r++) {
        int row  = tr * 8 + r;
        int grow = row0 + row;
        float h[8];
        float part = 0.0f;
#pragma unroll
        for (int c = 0; c < 8; c++) {
            h[c] = fmaxf(acc[r][c] + bvec[c], 0.0f);
            part += h[c] * wvec[c];
        }
        spart[row * 16 + tc] = part;
        if (grow < M) {
            float* dstp = hout + (long long)grow * FD;
            *(float4*)(dstp + tc * 4)      = make_float4(h[0], h[1], h[2], h[3]);
            *(float4*)(dstp + 64 + tc * 4) = make_float4(h[4], h[5], h[6], h[7]);
        }
    }
    __syncthreads();
    if (tid < 64) {
        int grow = row0 + tid;
        if (grow < M) {
            float dot = 0.0f;
#pragma unroll
            for (int i = 0; i < 16; i++) dot += spart[tid * 16 + i];
            float nr = 0.0f;
#pragma unroll
            for (int i = 0; i < 16; i++) nr += snrmp[i];
            score[grow] = tanhf(dot / sqrtf(nr));
        }
    }
}

// ---------------- fused per-graph tail: top-k sort + mapping + gather*score +
// readout (+ optional MLP head on the last layer) ----------------
// One block per graph, 1024 threads. mode: 0 = z=, 1 = z+=, 2 = z-final + head.
__global__ __launch_bounds__(1024) void topk_gather_readout_kernel(
        const float* __restrict__ score, const float* __restrict__ hout,
        int n_per, int k, int SN,
        float* __restrict__ xp, int* __restrict__ mapping,
        int* __restrict__ next_deg,
        float* __restrict__ z, int mode,
        const float* __restrict__ W1, const float* __restrict__ b1,
        const float* __restrict__ W2, const float* __restrict__ b2,
        const float* __restrict__ W3, const float* __restrict__ b3,
        float* __restrict__ out) {
    __shared__ float skey[512];
    __shared__ int   sidx[512];
    __shared__ float pmax[1024];
    __shared__ float psum[1024];
    __shared__ float zs[256], t1[128], t2[64], t3[16];
    int b = blockIdx.x, tid = threadIdx.x;

    for (int i = tid; i < SN; i += 1024) {
        if (i < n_per) { skey[i] = score[b * n_per + i]; sidx[i] = i; }
        else           { skey[i] = -INFINITY;            sidx[i] = 0x7fffffff; }
    }
    for (int i = tid; i < n_per; i += 1024) mapping[b * n_per + i] = -1;
    if (next_deg) for (int i = tid; i < k; i += 1024) next_deg[b * k + i] = 0;
    __syncthreads();

    // bitonic sort: desc value, tie -> asc index (jax.lax.top_k order)
    for (int ks = 2; ks <= SN; ks <<= 1) {
        for (int j = ks >> 1; j > 0; j >>= 1) {
            for (int i = tid; i < SN; i += 1024) {
                int l = i ^ j;
                if (l > i) {
                    float ki = skey[i], kl = skey[l];
                    int   ii = sidx[i], il = sidx[l];
                    bool before = (ki > kl) || (ki == kl && ii < il);
                    bool up = ((i & ks) == 0);
                    if (up ? !before : before) {
                        skey[i] = kl; skey[l] = ki;
                        sidx[i] = il; sidx[l] = ii;
                    }
                }
            }
            __syncthreads();
        }
    }

    for (int i = tid; i < k; i += 1024) mapping[b * n_per + sidx[i]] = b * k + i;

    int c = tid & 127, s = tid >> 7;
    float mx = -INFINITY, sm = 0.0f;
    for (int r = s; r < k; r += 8) {
        long long g = (long long)(b * n_per + sidx[r]) * FD + c;
        float v = hout[g] * skey[r];
        xp[(long long)(b * k + r) * FD + c] = v;
        mx = fmaxf(mx, v); sm += v;
    }
    pmax[tid] = mx; psum[tid] = sm;
    __syncthreads();
    if (tid < 128) {
        float m = -INFINITY, su = 0.0f;
#pragma unroll
        for (int i = 0; i < 8; i++) {
            m = fmaxf(m, pmax[i * 128 + tid]);
            su += psum[i * 128 + tid];
        }
        float mean = su / (float)k;
        if (mode == 0)      { z[b * 256 + tid] = m;  z[b * 256 + 128 + tid] = mean;  }
        else if (mode == 1) { z[b * 256 + tid] += m; z[b * 256 + 128 + tid] += mean; }
        else {
            zs[tid]       = z[b * 256 + tid] + m;
            zs[128 + tid] = z[b * 256 + 128 + tid] + mean;
        }
    }
    if (mode == 2) {
        __syncthreads();
        if (tid < 128) {
            float a = b1[tid];
            for (int kk = 0; kk < 256; kk++) a += zs[kk] * W1[kk * 128 + tid];
            t1[tid] = fmaxf(a, 0.0f);
        }
        __syncthreads();
        if (tid < 64) {
            float a = b2[tid];
            for (int kk = 0; kk < 128; kk++) a += t1[kk] * W2[kk * 64 + tid];
            t2[tid] = fmaxf(a, 0.0f);
        }
        __syncthreads();
        if (tid < 10) {
            float a = b3[tid];
            for (int kk = 0; kk < 64; kk++) a += t2[kk] * W3[kk * 10 + tid];
            t3[tid] = a;
        }
        __syncthreads();
        if (tid == 0) {
            float m = -INFINITY;
            for (int i = 0; i < 10; i++) m = fmaxf(m, t3[i]);
            float su = 0.0f;
            for (int i = 0; i < 10; i++) su += expf(t3[i] - m);
            float ls = logf(su);
            for (int i = 0; i < 10; i++) out[b * 10 + i] = t3[i] - m - ls;
        }
    }
}

extern "C" void kernel_launch(void* const* d_in, const int* in_sizes, int n_in,
                              void* d_out, int out_size, void* d_ws, size_t ws_size,
                              hipStream_t stream) {
    (void)in_sizes; (void)n_in; (void)out_size; (void)ws_size;
    const float* x   = (const float*)d_in[0];
    const int*   ei  = (const int*)d_in[1];
    const float* Wl1 = (const float*)d_in[2];
    const float* bl1 = (const float*)d_in[3];
    const float* Wr1 = (const float*)d_in[4];
    const float* Wl2 = (const float*)d_in[5];
    const float* bl2 = (const float*)d_in[6];
    const float* Wr2 = (const float*)d_in[7];
    const float* Wl3 = (const float*)d_in[8];
    const float* bl3 = (const float*)d_in[9];
    const float* Wr3 = (const float*)d_in[10];
    const float* pw1 = (const float*)d_in[11];
    const float* pw2 = (const float*)d_in[12];
    const float* pw3 = (const float*)d_in[13];
    const float* W1  = (const float*)d_in[14];
    const float* b1  = (const float*)d_in[15];
    const float* W2  = (const float*)d_in[16];
    const float* b2  = (const float*)d_in[17];
    const float* W3  = (const float*)d_in[18];
    const float* b3  = (const float*)d_in[19];
    float* out = (float*)d_out;

    // workspace layout
    char* ws = (char*)d_ws;
    size_t off = 0;
    auto alloc = [&](size_t bytes) {
        char* p = ws + off;
        off = (off + bytes + 255) & ~(size_t)255;
        return p;
    };
    float* hout  = (float*)alloc((size_t)NN * FD * 4);
    float* xp    = (float*)alloc((size_t)BG * K1 * FD * 4);
    float* sc    = (float*)alloc((size_t)NN * 4);
    int*   mapg  = (int*)  alloc((size_t)NN * 4);
    int*   srcb  = (int*)  alloc((size_t)EE * 4);
    int*   dstb  = (int*)  alloc((size_t)EE * 4);
    float* emb   = (float*)alloc((size_t)EE * 4);
    int*   deg   = (int*)  alloc((size_t)NN * 4);
    int*   colb  = (int*)  alloc((size_t)NN * CAP * 4);   // 12.8 MB
    float* z     = (float*)alloc((size_t)BG * 256 * 4);

    const int EB = (EE + 255) / 256;

    // ================= layer 1 =================
    hipMemsetAsync(deg, 0, (size_t)NN * 4, stream);
    fill_first_kernel<<<EB, 256, 0, stream>>>(ei, deg, colb, EE);
    sage_gemm_fused_kernel<<<(NN + 63) / 64, 128, 0, stream>>>(deg, colb, x, Wl1, Wr1, bl1, pw1,
                                                               hout, sc, NN);
    topk_gather_readout_kernel<<<BG, 1024, 0, stream>>>(sc, hout, NPG, K1, 512, xp, mapg, deg,
                                                        z, 0, W1, b1, W2, b2, W3, b3, out);

    // ================= layer 2 =================
    const int N2 = BG * K1;   // 25000
    remap_fill_first_kernel<<<EB, 256, 0, stream>>>(ei, mapg, srcb, dstb, emb, deg, colb, EE);
    sage_gemm_fused_kernel<<<(N2 + 63) / 64, 128, 0, stream>>>(deg, colb, xp, Wl2, Wr2, bl2, pw2,
                                                               hout, sc, N2);
    topk_gather_readout_kernel<<<BG, 1024, 0, stream>>>(sc, hout, K1, K2, 256, xp, mapg, deg,
                                                        z, 1, W1, b1, W2, b2, W3, b3, out);

    // ================= layer 3 =================
    const int N3 = BG * K2;   // 12500
    remap_fill_kernel<<<EB, 256, 0, stream>>>(srcb, dstb, emb, mapg, deg, colb, EE);
    sage_gemm_fused_kernel<<<(N3 + 63) / 64, 128, 0, stream>>>(deg, colb, xp, Wl3, Wr3, bl3, pw3,
                                                               hout, sc, N3);
    topk_gather_readout_kernel<<<BG, 1024, 0, stream>>>(sc, hout, K2, K3, 128, xp, mapg, (int*)0,
                                                        z, 2, W1, b1, W2, b2, W3, b3, out);
}

// Round 7
// 382.259 us; speedup vs baseline: 1.7881x; 1.7881x over previous
//
#include <hip/hip_runtime.h>
#include <math.h>

// Problem constants (from reference)
#define BG    100        // graphs
#define NPG   500        // nodes per graph (layer 1)
#define FD    128        // feature dim (F_IN == H == 128)
#define EE    600000     // edges
#define NN    50000      // total nodes layer 1
#define K1    250
#define K2    125
#define K3    63
#define CAP   64         // max in-degree capacity (in-deg ~ Poisson(12); P(>64) ~ 1e-30)

// ---------------- slot-CSR build: one edge pass, no scan ----------------
__global__ void fill_first_kernel(const int* __restrict__ ei, int* __restrict__ deg,
                                  int* __restrict__ col, int E) {
    int e = blockIdx.x * blockDim.x + threadIdx.x;
    if (e >= E) return;
    int d = ei[E + e];
    int pos = atomicAdd(&deg[d], 1);
    if (pos < CAP) col[d * CAP + pos] = ei[e];
}

// remap original edges through layer-1 pooling, store remapped edges for layer 3,
// and fill layer-2 neighbor slots — all in one pass
__global__ void remap_fill_first_kernel(const int* __restrict__ ei, const int* __restrict__ mapping,
                                        int* __restrict__ src, int* __restrict__ dst,
                                        float* __restrict__ em, int* __restrict__ deg,
                                        int* __restrict__ col, int E) {
    int e = blockIdx.x * blockDim.x + threadIdx.x;
    if (e >= E) return;
    int ns = mapping[ei[e]], nd = mapping[ei[E + e]];
    bool keep = (ns >= 0) && (nd >= 0);
    em[e]  = keep ? 1.0f : 0.0f;
    src[e] = keep ? ns : 0;
    dst[e] = keep ? nd : 0;
    if (keep) {
        int pos = atomicAdd(&deg[nd], 1);
        if (pos < CAP) col[nd * CAP + pos] = ns;
    }
}

// remap layer-2 edges through layer-2 pooling and fill layer-3 slots
__global__ void remap_fill_kernel(const int* __restrict__ src, const int* __restrict__ dst,
                                  const float* __restrict__ em, const int* __restrict__ mapping,
                                  int* __restrict__ deg, int* __restrict__ col, int E) {
    int e = blockIdx.x * blockDim.x + threadIdx.x;
    if (e >= E) return;
    if (em[e] == 0.0f) return;
    int ns = mapping[src[e]], nd = mapping[dst[e]];
    if (ns >= 0 && nd >= 0) {
        int pos = atomicAdd(&deg[nd], 1);
        if (pos < CAP) col[nd * CAP + pos] = ns;
    }
}

// ---------------- gather-aggregate: mean of neighbor rows ----------------
// float4 per lane: 32 lanes per node, 2 nodes per wave. High occupancy hides
// the pointer-chase latency (8 VGPR, thousands of waves) — do NOT fuse this
// into the occupancy-capped GEMM (R6 regression: 2 waves/SIMD, 5x FETCH).
__global__ void gather_agg_kernel(const int* __restrict__ deg, const int* __restrict__ col,
                                  const float* __restrict__ x, float* __restrict__ mean, int n) {
    int g = blockIdx.x * blockDim.x + threadIdx.x;
    int node = g >> 5, sub = g & 31;
    if (node >= n) return;
    int d = deg[node]; if (d > CAP) d = CAP;
    const int* cp = col + node * CAP;
    float ax = 0.0f, ay = 0.0f, az = 0.0f, aw = 0.0f;
    for (int j = 0; j < d; ++j) {
        int s = cp[j];
        float4 v = ((const float4*)(x + (long long)s * FD))[sub];
        ax += v.x; ay += v.y; az += v.z; aw += v.w;
    }
    float inv = 1.0f / fmaxf((float)d, 1.0f);
    float4 o; o.x = ax * inv; o.y = ay * inv; o.z = az * inv; o.w = aw * inv;
    ((float4*)(mean + (long long)node * FD))[sub] = o;
}

// ---------------- fused SAGE GEMM + score epilogue ----------------
// h = relu(mean@Wl + x@Wr + bl); score = tanh(h.pw / ||pw||)
// Tile 128 rows x 128 cols, 256 threads, 8x8 micro-tile, K=256 logical (mean|x).
// LDS ~41.5 KB -> 3 blocks/CU. 0.5 B LDS-read per FLOP.
__global__ __launch_bounds__(256) void sage_gemm_kernel(
        const float* __restrict__ mean, const float* __restrict__ x,
        const float* __restrict__ Wl, const float* __restrict__ Wr,
        const float* __restrict__ bl, const float* __restrict__ pw,
        float* __restrict__ hout, float* __restrict__ score, int M) {
    __shared__ __align__(16) float As[32 * 132];   // [kk][row], stride 132
    __shared__ __align__(16) float Ws[32 * 128];   // [kk][col]
    __shared__ float spart[128 * 16];
    __shared__ float snrmp[16];
    int tid  = threadIdx.x;
    int row0 = blockIdx.x * 128;
    int tr   = tid >> 4;             // 0..15 -> rows 8*tr..8*tr+7
    int tc   = tid & 15;             // 0..15 -> cols {4tc..4tc+3, 64+4tc..64+4tc+3}
    float acc[8][8];
#pragma unroll
    for (int r = 0; r < 8; r++)
#pragma unroll
        for (int c = 0; c < 8; c++) acc[r][c] = 0.0f;

    int lrow  = tid >> 1;            // 0..127
    int lkoff = (tid & 1) << 4;      // 0 or 16
    int wc    = (tid & 31) << 2;     // 0..124
    int wk0   = tid >> 5;            // 0..7

    for (int kt = 0; kt < 8; ++kt) {
        bool isMean = kt < 4;
        const float* Ab = isMean ? mean : x;
        {
            int grow = row0 + lrow; if (grow > M - 1) grow = M - 1;
            const float* ar = Ab + (long long)grow * FD + (isMean ? kt : kt - 4) * 32 + lkoff;
#pragma unroll
            for (int q = 0; q < 4; ++q) {
                float4 v = *(const float4*)(ar + (q << 2));
                int kb = lkoff + (q << 2);
                As[(kb + 0) * 132 + lrow] = v.x;
                As[(kb + 1) * 132 + lrow] = v.y;
                As[(kb + 2) * 132 + lrow] = v.z;
                As[(kb + 3) * 132 + lrow] = v.w;
            }
        }
        {
            const float* WB = isMean ? Wl : Wr;
            int krow0 = (isMean ? kt : kt - 4) * 32;
#pragma unroll
            for (int q = 0; q < 4; ++q) {
                int kk = wk0 + (q << 3);
                *(float4*)&Ws[kk * 128 + wc] = *(const float4*)(WB + (long long)(krow0 + kk) * FD + wc);
            }
        }
        __syncthreads();
#pragma unroll
        for (int kk = 0; kk < 32; ++kk) {
            float4 a0 = *(const float4*)&As[kk * 132 + tr * 8];
            float4 a1 = *(const float4*)&As[kk * 132 + tr * 8 + 4];
            float4 b0 = *(const float4*)&Ws[kk * 128 + tc * 4];
            float4 b1 = *(const float4*)&Ws[kk * 128 + 64 + tc * 4];
            float av[8] = {a0.x, a0.y, a0.z, a0.w, a1.x, a1.y, a1.z, a1.w};
            float bv[8] = {b0.x, b0.y, b0.z, b0.w, b1.x, b1.y, b1.z, b1.w};
#pragma unroll
            for (int r = 0; r < 8; r++)
#pragma unroll
                for (int c = 0; c < 8; c++) acc[r][c] += av[r] * bv[c];
        }
        __syncthreads();
    }

    // epilogue: bias + relu + store h, score partials
    float4 bb0 = *(const float4*)(bl + tc * 4);
    float4 bb1 = *(const float4*)(bl + 64 + tc * 4);
    float4 w0  = *(const float4*)(pw + tc * 4);
    float4 w1  = *(const float4*)(pw + 64 + tc * 4);
    float bvec[8] = {bb0.x, bb0.y, bb0.z, bb0.w, bb1.x, bb1.y, bb1.z, bb1.w};
    float wvec[8] = {w0.x, w0.y, w0.z, w0.w, w1.x, w1.y, w1.z, w1.w};
    if (tr == 0) snrmp[tc] = w0.x*w0.x + w0.y*w0.y + w0.z*w0.z + w0.w*w0.w +
                             w1.x*w1.x + w1.y*w1.y + w1.z*w1.z + w1.w*w1.w;
#pragma unroll
    for (int r = 0; r < 8; r++) {
        int row  = tr * 8 + r;
        int grow = row0 + row;
        float h[8];
        float part = 0.0f;
#pragma unroll
        for (int c = 0; c < 8; c++) {
            h[c] = fmaxf(acc[r][c] + bvec[c], 0.0f);
            part += h[c] * wvec[c];
        }
        spart[row * 16 + tc] = part;
        if (grow < M) {
            float* dstp = hout + (long long)grow * FD;
            *(float4*)(dstp + tc * 4)      = make_float4(h[0], h[1], h[2], h[3]);
            *(float4*)(dstp + 64 + tc * 4) = make_float4(h[4], h[5], h[6], h[7]);
        }
    }
    __syncthreads();
    if (tid < 128) {
        int grow = row0 + tid;
        if (grow < M) {
            float dot = 0.0f;
#pragma unroll
            for (int i = 0; i < 16; i++) dot += spart[tid * 16 + i];
            float nr = 0.0f;
#pragma unroll
            for (int i = 0; i < 16; i++) nr += snrmp[i];
            score[grow] = tanhf(dot / sqrtf(nr));
        }
    }
}

// ---------------- fused per-graph tail: top-k sort + mapping + gather*score +
// readout (+ optional MLP head on the last layer) ----------------
// One block per graph, 1024 threads. mode: 0 = z=, 1 = z+=, 2 = z-final + head.
__global__ __launch_bounds__(1024) void topk_gather_readout_kernel(
        const float* __restrict__ score, const float* __restrict__ hout,
        int n_per, int k, int SN,
        float* __restrict__ xp, int* __restrict__ mapping,
        int* __restrict__ next_deg,
        float* __restrict__ z, int mode,
        const float* __restrict__ W1, const float* __restrict__ b1,
        const float* __restrict__ W2, const float* __restrict__ b2,
        const float* __restrict__ W3, const float* __restrict__ b3,
        float* __restrict__ out) {
    __shared__ float skey[512];
    __shared__ int   sidx[512];
    __shared__ float pmax[1024];
    __shared__ float psum[1024];
    __shared__ float zs[256], t1[128], t2[64], t3[16];
    int b = blockIdx.x, tid = threadIdx.x;

    for (int i = tid; i < SN; i += 1024) {
        if (i < n_per) { skey[i] = score[b * n_per + i]; sidx[i] = i; }
        else           { skey[i] = -INFINITY;            sidx[i] = 0x7fffffff; }
    }
    for (int i = tid; i < n_per; i += 1024) mapping[b * n_per + i] = -1;
    if (next_deg) for (int i = tid; i < k; i += 1024) next_deg[b * k + i] = 0;
    __syncthreads();

    // bitonic sort: desc value, tie -> asc index (jax.lax.top_k order)
    for (int ks = 2; ks <= SN; ks <<= 1) {
        for (int j = ks >> 1; j > 0; j >>= 1) {
            for (int i = tid; i < SN; i += 1024) {
                int l = i ^ j;
                if (l > i) {
                    float ki = skey[i], kl = skey[l];
                    int   ii = sidx[i], il = sidx[l];
                    bool before = (ki > kl) || (ki == kl && ii < il);
                    bool up = ((i & ks) == 0);
                    if (up ? !before : before) {
                        skey[i] = kl; skey[l] = ki;
                        sidx[i] = il; sidx[l] = ii;
                    }
                }
            }
            __syncthreads();
        }
    }

    for (int i = tid; i < k; i += 1024) mapping[b * n_per + sidx[i]] = b * k + i;

    int c = tid & 127, s = tid >> 7;
    float mx = -INFINITY, sm = 0.0f;
    for (int r = s; r < k; r += 8) {
        long long g = (long long)(b * n_per + sidx[r]) * FD + c;
        float v = hout[g] * skey[r];
        xp[(long long)(b * k + r) * FD + c] = v;
        mx = fmaxf(mx, v); sm += v;
    }
    pmax[tid] = mx; psum[tid] = sm;
    __syncthreads();
    if (tid < 128) {
        float m = -INFINITY, su = 0.0f;
#pragma unroll
        for (int i = 0; i < 8; i++) {
            m = fmaxf(m, pmax[i * 128 + tid]);
            su += psum[i * 128 + tid];
        }
        float mean = su / (float)k;
        if (mode == 0)      { z[b * 256 + tid] = m;  z[b * 256 + 128 + tid] = mean;  }
        else if (mode == 1) { z[b * 256 + tid] += m; z[b * 256 + 128 + tid] += mean; }
        else {
            zs[tid]       = z[b * 256 + tid] + m;
            zs[128 + tid] = z[b * 256 + 128 + tid] + mean;
        }
    }
    if (mode == 2) {
        __syncthreads();
        if (tid < 128) {
            float a = b1[tid];
            for (int kk = 0; kk < 256; kk++) a += zs[kk] * W1[kk * 128 + tid];
            t1[tid] = fmaxf(a, 0.0f);
        }
        __syncthreads();
        if (tid < 64) {
            float a = b2[tid];
            for (int kk = 0; kk < 128; kk++) a += t1[kk] * W2[kk * 64 + tid];
            t2[tid] = fmaxf(a, 0.0f);
        }
        __syncthreads();
        if (tid < 10) {
            float a = b3[tid];
            for (int kk = 0; kk < 64; kk++) a += t2[kk] * W3[kk * 10 + tid];
            t3[tid] = a;
        }
        __syncthreads();
        if (tid == 0) {
            float m = -INFINITY;
            for (int i = 0; i < 10; i++) m = fmaxf(m, t3[i]);
            float su = 0.0f;
            for (int i = 0; i < 10; i++) su += expf(t3[i] - m);
            float ls = logf(su);
            for (int i = 0; i < 10; i++) out[b * 10 + i] = t3[i] - m - ls;
        }
    }
}

extern "C" void kernel_launch(void* const* d_in, const int* in_sizes, int n_in,
                              void* d_out, int out_size, void* d_ws, size_t ws_size,
                              hipStream_t stream) {
    (void)in_sizes; (void)n_in; (void)out_size; (void)ws_size;
    const float* x   = (const float*)d_in[0];
    const int*   ei  = (const int*)d_in[1];
    const float* Wl1 = (const float*)d_in[2];
    const float* bl1 = (const float*)d_in[3];
    const float* Wr1 = (const float*)d_in[4];
    const float* Wl2 = (const float*)d_in[5];
    const float* bl2 = (const float*)d_in[6];
    const float* Wr2 = (const float*)d_in[7];
    const float* Wl3 = (const float*)d_in[8];
    const float* bl3 = (const float*)d_in[9];
    const float* Wr3 = (const float*)d_in[10];
    const float* pw1 = (const float*)d_in[11];
    const float* pw2 = (const float*)d_in[12];
    const float* pw3 = (const float*)d_in[13];
    const float* W1  = (const float*)d_in[14];
    const float* b1  = (const float*)d_in[15];
    const float* W2  = (const float*)d_in[16];
    const float* b2  = (const float*)d_in[17];
    const float* W3  = (const float*)d_in[18];
    const float* b3  = (const float*)d_in[19];
    float* out = (float*)d_out;

    // workspace layout
    char* ws = (char*)d_ws;
    size_t off = 0;
    auto alloc = [&](size_t bytes) {
        char* p = ws + off;
        off = (off + bytes + 255) & ~(size_t)255;
        return p;
    };
    float* mean  = (float*)alloc((size_t)NN * FD * 4);
    float* hout  = (float*)alloc((size_t)NN * FD * 4);
    float* xp    = (float*)alloc((size_t)BG * K1 * FD * 4);
    float* sc    = (float*)alloc((size_t)NN * 4);
    int*   mapg  = (int*)  alloc((size_t)NN * 4);
    int*   srcb  = (int*)  alloc((size_t)EE * 4);
    int*   dstb  = (int*)  alloc((size_t)EE * 4);
    float* emb   = (float*)alloc((size_t)EE * 4);
    int*   deg   = (int*)  alloc((size_t)NN * 4);
    int*   colb  = (int*)  alloc((size_t)NN * CAP * 4);   // 12.8 MB
    float* z     = (float*)alloc((size_t)BG * 256 * 4);

    const int EB = (EE + 255) / 256;

    // ================= layer 1 =================
    hipMemsetAsync(deg, 0, (size_t)NN * 4, stream);
    fill_first_kernel<<<EB, 256, 0, stream>>>(ei, deg, colb, EE);
    gather_agg_kernel<<<(NN * 32 + 255) / 256, 256, 0, stream>>>(deg, colb, x, mean, NN);
    sage_gemm_kernel<<<(NN + 127) / 128, 256, 0, stream>>>(mean, x, Wl1, Wr1, bl1, pw1, hout, sc, NN);
    topk_gather_readout_kernel<<<BG, 1024, 0, stream>>>(sc, hout, NPG, K1, 512, xp, mapg, deg,
                                                        z, 0, W1, b1, W2, b2, W3, b3, out);

    // ================= layer 2 =================
    const int N2 = BG * K1;   // 25000
    remap_fill_first_kernel<<<EB, 256, 0, stream>>>(ei, mapg, srcb, dstb, emb, deg, colb, EE);
    gather_agg_kernel<<<(N2 * 32 + 255) / 256, 256, 0, stream>>>(deg, colb, xp, mean, N2);
    sage_gemm_kernel<<<(N2 + 127) / 128, 256, 0, stream>>>(mean, xp, Wl2, Wr2, bl2, pw2, hout, sc, N2);
    topk_gather_readout_kernel<<<BG, 1024, 0, stream>>>(sc, hout, K1, K2, 256, xp, mapg, deg,
                                                        z, 1, W1, b1, W2, b2, W3, b3, out);

    // ================= layer 3 =================
    const int N3 = BG * K2;   // 12500
    remap_fill_kernel<<<EB, 256, 0, stream>>>(srcb, dstb, emb, mapg, deg, colb, EE);
    gather_agg_kernel<<<(N3 * 32 + 255) / 256, 256, 0, stream>>>(deg, colb, xp, mean, N3);
    sage_gemm_kernel<<<(N3 + 127) / 128, 256, 0, stream>>>(mean, xp, Wl3, Wr3, bl3, pw3, hout, sc, N3);
    topk_gather_readout_kernel<<<BG, 1024, 0, stream>>>(sc, hout, K2, K3, 128, xp, mapg, (int*)0,
                                                        z, 2, W1, b1, W2, b2, W3, b3, out);
}